// Round 11
// baseline (156.008 us; speedup 1.0000x reference)
//
#include <hip/hip_runtime.h>
#include <math.h>

#define DIM 64
#define KC 32
#define NPTS 32768
#define LOG_2PI 1.8378770664093453f
#define C0 (-58.0f)   // fixed logsumexp reference: logp <= -58.81 always (logdet>=0, logw<=0)
#define ST 68         // prep LDS row stride (words): mult of 4 -> 16B-aligned float4 rows/cols

typedef __attribute__((ext_vector_type(8))) short short8;
typedef __attribute__((ext_vector_type(4))) float float4v;

__device__ __forceinline__ unsigned short f2bf(float f) {
    unsigned u = __float_as_uint(f);
    u += 0x7FFFu + ((u >> 16) & 1u);   // RNE
    return (unsigned short)(u >> 16);
}

__device__ __forceinline__ float rdlane(float v, int l) {
    return __int_as_float(__builtin_amdgcn_readlane(__float_as_int(v), l));
}

// DPP adds (VALU pipe, not LDS) — HW-verified correct in rounds 7-10.
template <int CTRL>
__device__ __forceinline__ float dpp_add(float x) {
    int t = __builtin_amdgcn_mov_dpp(__float_as_int(x), CTRL, 0xF, 0xF, true);
    return x + __int_as_float(t);
}
__device__ __forceinline__ float sum16(float x) {   // sum within each 16-lane row
    x = dpp_add<0xB1>(x);    // quad_perm [1,0,3,2]  : xor 1
    x = dpp_add<0x4E>(x);    // quad_perm [2,3,0,1]  : xor 2
    x = dpp_add<0x141>(x);   // row_half_mirror      : xor 4
    x = dpp_add<0x140>(x);   // row_mirror           : xor 8
    return x;
}

// ============================================================================
// Prep: FROZEN from round 10 (31.8 us measured) except the one-line counter
// zero for main's folded final reduction. 4-col blocked two-wave Cholesky +
// inverse; see r10 notes for invariants.
// ============================================================================
__global__ __launch_bounds__(256) void prep_kernel(
    const float* __restrict__ L, const float* __restrict__ mu,
    const float* __restrict__ w, short* __restrict__ Bpack,
    float* __restrict__ cstC, int* __restrict__ counter)
{
    const int k = blockIdx.x;
    const int t = threadIdx.x;
    const int wv = t >> 6;
    const int ln = t & 63;
    __shared__ float Llds[DIM * ST];
    __shared__ float Sig[DIM * ST];
    __shared__ float Clds[DIM * ST];
    __shared__ float Ylds[DIM * ST];   // Ylds[a*ST + b] = M[b][a]
    __shared__ float qlds[DIM];
    __shared__ float rdbuf[DIM];
    __shared__ float ldet;

    if (k == 0 && t == 0) *counter = 0;   // main's atomic-tail counter

    for (int idx = t; idx < DIM * DIM; idx += 256) {
        int r = idx >> 6, c = idx & 63;
        float v = L[(size_t)k * DIM * DIM + idx];
        Llds[r * ST + c] = (c <= r) ? v : 0.f;
    }
    for (int idx = t; idx < DIM * ST; idx += 256) {
        Clds[idx] = 0.f;
        Ylds[idx] = 0.f;
    }
    __syncthreads();

    {
        float Lr[DIM];
        const float2* lp = (const float2*)(Llds + ln * ST);
#pragma unroll
        for (int p = 0; p < 32; ++p) {
            float2 v = lp[p];
            Lr[2 * p] = v.x; Lr[2 * p + 1] = v.y;
        }
#pragma unroll 1
        for (int jj = 0; jj < 16; ++jj) {
            const int j = wv * 16 + jj;
            const float2* up = (const float2*)(Llds + j * ST);
            float a0 = 0.f, a1 = 0.f, a2 = 0.f, a3 = 0.f;
#pragma unroll
            for (int p = 0; p < 32; p += 2) {
                float2 u0 = up[p], u1 = up[p + 1];
                a0 = fmaf(Lr[2 * p], u0.x, a0);
                a1 = fmaf(Lr[2 * p + 1], u0.y, a1);
                a2 = fmaf(Lr[2 * p + 2], u1.x, a2);
                a3 = fmaf(Lr[2 * p + 3], u1.y, a3);
            }
            float s = (a0 + a1) + (a2 + a3);
            if (j == ln) s += 1.f;
            Sig[ln * ST + j] = s;
        }
    }
    __syncthreads();

    {
        const float2* crow = (const float2*)(Clds + ln * ST);
        const float2* yrow = (const float2*)(Ylds + ln * ST);
        float ld2 = 0.f;
#pragma unroll 1
        for (int c = 0; c < DIM; c += 4) {
            const float2* u0 = (const float2*)(Clds + (c + 0) * ST);
            const float2* u1 = (const float2*)(Clds + (c + 1) * ST);
            const float2* u2 = (const float2*)(Clds + (c + 2) * ST);
            const float2* u3 = (const float2*)(Clds + (c + 3) * ST);
            float si0 = 0.f, si1 = 0.f, si2 = 0.f, si3 = 0.f;
            if (wv == 0) {
                float d0a = 0.f, d0b = 0.f, d1a = 0.f, d1b = 0.f;
                float d2a = 0.f, d2b = 0.f, d3a = 0.f, d3b = 0.f;
#pragma unroll
                for (int p = 0; p < 32; ++p) {
                    float2 cr = crow[p];
                    float2 a0 = u0[p], a1 = u1[p], a2 = u2[p], a3 = u3[p];
                    d0a = fmaf(cr.x, a0.x, d0a); d0b = fmaf(cr.y, a0.y, d0b);
                    d1a = fmaf(cr.x, a1.x, d1a); d1b = fmaf(cr.y, a1.y, d1b);
                    d2a = fmaf(cr.x, a2.x, d2a); d2b = fmaf(cr.y, a2.y, d2b);
                    d3a = fmaf(cr.x, a3.x, d3a); d3b = fmaf(cr.y, a3.y, d3b);
                }
                const float4 sg = *(const float4*)(Sig + ln * ST + c);
                float s0 = sg.x - (d0a + d0b);
                float s1 = sg.y - (d1a + d1b);
                float s2 = sg.z - (d2a + d2b);
                float s3 = sg.w - (d3a + d3b);
                float dd0 = rdlane(s0, c + 0);
                float rd0 = __builtin_amdgcn_rsqf(dd0);
                float c0v = s0 * rd0;
                s1 = fmaf(-c0v, rdlane(c0v, c + 1), s1);
                s2 = fmaf(-c0v, rdlane(c0v, c + 2), s2);
                s3 = fmaf(-c0v, rdlane(c0v, c + 3), s3);
                float dd1 = rdlane(s1, c + 1);
                float rd1 = __builtin_amdgcn_rsqf(dd1);
                float c1v = s1 * rd1;
                s2 = fmaf(-c1v, rdlane(c1v, c + 2), s2);
                s3 = fmaf(-c1v, rdlane(c1v, c + 3), s3);
                float dd2 = rdlane(s2, c + 2);
                float rd2 = __builtin_amdgcn_rsqf(dd2);
                float c2v = s2 * rd2;
                s3 = fmaf(-c2v, rdlane(c2v, c + 3), s3);
                float dd3 = rdlane(s3, c + 3);
                float rd3 = __builtin_amdgcn_rsqf(dd3);
                float c3v = s3 * rd3;
                ld2 += (__logf(dd0) + __logf(dd1)) + (__logf(dd2) + __logf(dd3));
                *(float4*)(Clds + ln * ST + c) = make_float4(c0v, c1v, c2v, c3v);
                if (ln == 0) *(float4*)(rdbuf + c) = make_float4(rd0, rd1, rd2, rd3);
            } else if (wv == 1) {
                float e0a = 0.f, e0b = 0.f, e1a = 0.f, e1b = 0.f;
                float e2a = 0.f, e2b = 0.f, e3a = 0.f, e3b = 0.f;
#pragma unroll
                for (int p = 0; p < 32; ++p) {
                    float2 yr = yrow[p];
                    float2 a0 = u0[p], a1 = u1[p], a2 = u2[p], a3 = u3[p];
                    e0a = fmaf(yr.x, a0.x, e0a); e0b = fmaf(yr.y, a0.y, e0b);
                    e1a = fmaf(yr.x, a1.x, e1a); e1b = fmaf(yr.y, a1.y, e1b);
                    e2a = fmaf(yr.x, a2.x, e2a); e2b = fmaf(yr.y, a2.y, e2b);
                    e3a = fmaf(yr.x, a3.x, e3a); e3b = fmaf(yr.y, a3.y, e3b);
                }
                si0 = ((ln == c + 0) ? 1.f : 0.f) - (e0a + e0b);
                si1 = ((ln == c + 1) ? 1.f : 0.f) - (e1a + e1b);
                si2 = ((ln == c + 2) ? 1.f : 0.f) - (e2a + e2b);
                si3 = ((ln == c + 3) ? 1.f : 0.f) - (e3a + e3b);
            }
            __syncthreads();
            if (wv == 1) {
                const float4 rdv = *(const float4*)(rdbuf + c);
                float C10 = Clds[(c + 1) * ST + c];
                float C20 = Clds[(c + 2) * ST + c];
                float C21 = Clds[(c + 2) * ST + c + 1];
                float C30 = Clds[(c + 3) * ST + c];
                float C31 = Clds[(c + 3) * ST + c + 1];
                float C32 = Clds[(c + 3) * ST + c + 2];
                float y0 = si0 * rdv.x;
                float y1 = (si1 - C10 * y0) * rdv.y;
                float y2 = (si2 - C20 * y0 - C21 * y1) * rdv.z;
                float y3 = (si3 - C30 * y0 - C31 * y1 - C32 * y2) * rdv.w;
                float4 yo;
                yo.x = (ln <= c + 0) ? y0 : 0.f;
                yo.y = (ln <= c + 1) ? y1 : 0.f;
                yo.z = (ln <= c + 2) ? y2 : 0.f;
                yo.w = (ln <= c + 3) ? y3 : 0.f;
                *(float4*)(Ylds + ln * ST + c) = yo;
            }
        }
        if (wv == 0 && ln == 0) ldet = ld2;
    }
    __syncthreads();

    if (wv == 0) {
        const float* muk = mu + k * DIM;
        float qv = 0.f;
#pragma unroll 8
        for (int j = 0; j < DIM; ++j)
            qv = fmaf(Ylds[j * ST + ln], muk[j], qv);
        qlds[ln] = qv;
        if (ln == 0) {
            float wm = -3.0e38f;
            for (int i = 0; i < KC; ++i) wm = fmaxf(wm, w[i]);
            float se = 0.f;
            for (int i = 0; i < KC; ++i) se += __expf(w[i] - wm);
            float logw = w[k] - (wm + __logf(se));
            cstC[k] = -0.5f * (DIM * LOG_2PI + ldet) + logw - C0;
        }
    }
    __syncthreads();

    {
        const int ct = wv;
        const int col = ct * 16 + (ln & 15);
        const int kb = (ln >> 4) * 8;
#pragma unroll
        for (int kt = 0; kt < 3; ++kt) {
            short8 v;
            if (kt < 2) {
#pragma unroll
                for (int e = 0; e < 8; ++e)
                    v[e] = (short)f2bf(Ylds[(kt * 32 + kb + e) * ST + col]);
            } else {
#pragma unroll
                for (int e = 0; e < 8; ++e)
                    v[e] = (short)((kb + e == 0) ? f2bf(-qlds[col]) : 0);
            }
            *(short8*)(Bpack + ((size_t)(k * 12 + ct * 3 + kt) * 64 + ln) * 8) = v;
        }
    }
}

// ============================================================================
// Main v4: r8 skeleton (LDS-staged B, measured best) with:
//  (1) augmented-tile MFMAs dropped: bf16(-q) read from Bpack's aug fragment
//      (bit-identical rounding) and applied post-MFMA; 96 -> 64 MFMAs, LDS
//      stage 48 -> 32 KB;
//  (2) float4 X loads (was 32 lane-strided scalar loads);
//  (3) (256,4) occupancy; final_kernel folded in via r7-validated atomic tail.
// 2048 blocks x 256 thr; block = k-subset (4 comps) x 128 rows.
// ============================================================================
__global__ __launch_bounds__(256, 4) void main_kernel(
    const float* __restrict__ X, const short* __restrict__ Bpack,
    const float* __restrict__ cstC, float* __restrict__ partials,
    int* __restrict__ counter, float* __restrict__ out)
{
    const int tid = threadIdx.x;
    const int lane = tid & 63;
    const int wv = tid >> 6;
    const int ks = blockIdx.x & 7;         // k in [4ks, 4ks+4)
    const int g = blockIdx.x >> 3;         // row group: 128 rows

    __shared__ float4 Bsh[2048];           // 32 KB: 4kk x 4ct x 2kt x 64 lanes
    {
        const float4* Bg = (const float4*)Bpack;
#pragma unroll
        for (int it = 0; it < 8; ++it) {
            int flat = it * 256 + tid;
            int frag = flat >> 6, l2 = flat & 63;
            int kk2 = frag >> 3, ct2 = (frag >> 1) & 3, kt2 = frag & 1;
            Bsh[flat] = Bg[(size_t)(((ks * 4 + kk2) * 12 + ct2 * 3 + kt2) * 64 + l2)];
        }
    }

    // A fragments: 2 row-tiles x 2 K-halves, float4 loads.
    // elem e of a[tt][hh] = X[rbase + tt*16 + (lane&15)][hh*32 + (lane>>4)*8 + e]
    const int m = lane & 15;
    const int h8 = lane >> 4;              // 0..3
    const int rbase = g * 128 + wv * 32;
    short8 a[2][2];
#pragma unroll
    for (int tt = 0; tt < 2; ++tt) {
        const float4* Xr = (const float4*)(X + (size_t)(rbase + tt * 16 + m) * DIM);
#pragma unroll
        for (int hh = 0; hh < 2; ++hh) {
            float4 v0 = Xr[hh * 8 + h8 * 2];
            float4 v1 = Xr[hh * 8 + h8 * 2 + 1];
            a[tt][hh][0] = (short)f2bf(v0.x); a[tt][hh][1] = (short)f2bf(v0.y);
            a[tt][hh][2] = (short)f2bf(v0.z); a[tt][hh][3] = (short)f2bf(v0.w);
            a[tt][hh][4] = (short)f2bf(v1.x); a[tt][hh][5] = (short)f2bf(v1.y);
            a[tt][hh][6] = (short)f2bf(v1.z); a[tt][hh][7] = (short)f2bf(v1.w);
        }
    }
    __syncthreads();

    const short8* Bs = (const short8*)Bsh;
    float acc = 0.f;
#pragma unroll
    for (int kk = 0; kk < 4; ++kk) {
        const int k = ks * 4 + kk;
        float p0 = 0.f, p1 = 0.f, p2 = 0.f, p3 = 0.f;
        float r0 = 0.f, r1 = 0.f, r2 = 0.f, r3 = 0.f;
#pragma unroll
        for (int ct = 0; ct < 4; ++ct) {
            short8 f0 = Bs[(kk * 8 + ct * 2 + 0) * 64 + lane];
            short8 f1 = Bs[(kk * 8 + ct * 2 + 1) * 64 + lane];
            // -q[k][ct*16+m], bf16-rounded exactly as the old aug-tile path
            short qs = Bpack[((size_t)(k * 12 + ct * 3 + 2) * 64 + m) * 8];
            float nq = __int_as_float(((int)(unsigned short)qs) << 16);
            float4v c0 = {0.f, 0.f, 0.f, 0.f};
            c0 = __builtin_amdgcn_mfma_f32_16x16x32_bf16(a[0][0], f0, c0, 0, 0, 0);
            c0 = __builtin_amdgcn_mfma_f32_16x16x32_bf16(a[0][1], f1, c0, 0, 0, 0);
            float4v c1 = {0.f, 0.f, 0.f, 0.f};
            c1 = __builtin_amdgcn_mfma_f32_16x16x32_bf16(a[1][0], f0, c1, 0, 0, 0);
            c1 = __builtin_amdgcn_mfma_f32_16x16x32_bf16(a[1][1], f1, c1, 0, 0, 0);
            float d;
            d = c0[0] + nq; p0 = fmaf(d, d, p0);
            d = c0[1] + nq; p1 = fmaf(d, d, p1);
            d = c0[2] + nq; p2 = fmaf(d, d, p2);
            d = c0[3] + nq; p3 = fmaf(d, d, p3);
            d = c1[0] + nq; r0 = fmaf(d, d, r0);
            d = c1[1] + nq; r1 = fmaf(d, d, r1);
            d = c1[2] + nq; r2 = fmaf(d, d, r2);
            d = c1[3] + nq; r3 = fmaf(d, d, r3);
        }
        const float cc = cstC[k];          // wave-uniform s_load
        acc += __expf(fmaf(-0.5f, sum16(p0), cc)) + __expf(fmaf(-0.5f, sum16(p1), cc));
        acc += __expf(fmaf(-0.5f, sum16(p2), cc)) + __expf(fmaf(-0.5f, sum16(p3), cc));
        acc += __expf(fmaf(-0.5f, sum16(r0), cc)) + __expf(fmaf(-0.5f, sum16(r1), cc));
        acc += __expf(fmaf(-0.5f, sum16(r2), cc)) + __expf(fmaf(-0.5f, sum16(r3), cc));
    }
    // the 4 lane-groups hold disjoint rows (in-group duplicates after sum16)
    acc += __shfl_xor(acc, 16, 64);
    acc += __shfl_xor(acc, 32, 64);

    __shared__ float pm[4];
    __shared__ int lastdone;
    if (lane == 0) pm[wv] = acc;
    __syncthreads();
    if (tid == 0) {
        partials[blockIdx.x] = (pm[0] + pm[1]) + (pm[2] + pm[3]);
        __threadfence();                          // release partials
        lastdone = (atomicAdd(counter, 1) == 2047) ? 1 : 0;
    }
    __syncthreads();
    if (lastdone) {                               // block-uniform
        __threadfence();                          // acquire others' partials
        float s = 0.f;
        for (int i = tid; i < 2048; i += 256) s += partials[i];
#pragma unroll
        for (int mm = 1; mm <= 32; mm <<= 1) s += __shfl_xor(s, mm, 64);
        if (lane == 0) pm[wv] = s;
        __syncthreads();
        if (tid == 0) out[0] = -(C0 + logf((pm[0] + pm[1]) + (pm[2] + pm[3])));
    }
}

extern "C" void kernel_launch(void* const* d_in, const int* in_sizes, int n_in,
                              void* d_out, int out_size, void* d_ws, size_t ws_size,
                              hipStream_t stream) {
    const float* X  = (const float*)d_in[0];   // [32768,64]
    const float* mu = (const float*)d_in[1];   // [32,64]
    const float* L  = (const float*)d_in[2];   // [32,64,64]
    const float* w  = (const float*)d_in[3];   // [32]
    // d_in[4] = it (unused)

    char* ws = (char*)d_ws;
    short* Bpack   = (short*)ws;                       // 32*12*64*8 bf16 = 384 KB
    float* cstC    = (float*)(ws + 32 * 12 * 64 * 8 * 2);
    float* parts   = cstC + KC;                        // 2048 floats
    int*   counter = (int*)(parts + 2048);

    prep_kernel<<<KC, 256, 0, stream>>>(L, mu, w, Bpack, cstC, counter);
    main_kernel<<<2048, 256, 0, stream>>>(X, Bpack, cstC, parts, counter, (float*)d_out);
}

// Round 12
// 113.274 us; speedup vs baseline: 1.3773x; 1.3773x over previous
//
#include <hip/hip_runtime.h>
#include <math.h>

#define DIM 64
#define KC 32
#define NPTS 32768
#define LOG_2PI 1.8378770664093453f
#define C0 (-58.0f)   // fixed logsumexp reference: logp <= -58.81 always (logdet>=0, logw<=0)
#define ST 68         // prep LDS row stride (words): mult of 4 -> 16B-aligned float4 rows/cols

typedef __attribute__((ext_vector_type(8))) short short8;
typedef __attribute__((ext_vector_type(4))) float float4v;

__device__ __forceinline__ unsigned short f2bf(float f) {
    unsigned u = __float_as_uint(f);
    u += 0x7FFFu + ((u >> 16) & 1u);   // RNE
    return (unsigned short)(u >> 16);
}

__device__ __forceinline__ float rdlane(float v, int l) {
    return __int_as_float(__builtin_amdgcn_readlane(__float_as_int(v), l));
}

// DPP adds (VALU pipe, not LDS) — HW-verified correct in rounds 7-11.
template <int CTRL>
__device__ __forceinline__ float dpp_add(float x) {
    int t = __builtin_amdgcn_mov_dpp(__float_as_int(x), CTRL, 0xF, 0xF, true);
    return x + __int_as_float(t);
}
__device__ __forceinline__ float sum16(float x) {   // sum within each 16-lane row
    x = dpp_add<0xB1>(x);    // quad_perm [1,0,3,2]  : xor 1
    x = dpp_add<0x4E>(x);    // quad_perm [2,3,0,1]  : xor 2
    x = dpp_add<0x141>(x);   // row_half_mirror      : xor 4
    x = dpp_add<0x140>(x);   // row_mirror           : xor 8
    return x;
}

// ============================================================================
// Prep: FROZEN r10 verbatim (measured ~31.8 us). 4-col blocked two-wave
// Cholesky + inverse; 16 serial steps. See r10 notes for invariants.
// ============================================================================
__global__ __launch_bounds__(256) void prep_kernel(
    const float* __restrict__ L, const float* __restrict__ mu,
    const float* __restrict__ w, short* __restrict__ Bpack,
    float* __restrict__ cstC)
{
    const int k = blockIdx.x;
    const int t = threadIdx.x;
    const int wv = t >> 6;
    const int ln = t & 63;
    __shared__ float Llds[DIM * ST];
    __shared__ float Sig[DIM * ST];
    __shared__ float Clds[DIM * ST];
    __shared__ float Ylds[DIM * ST];   // Ylds[a*ST + b] = M[b][a]
    __shared__ float qlds[DIM];
    __shared__ float rdbuf[DIM];
    __shared__ float ldet;

    for (int idx = t; idx < DIM * DIM; idx += 256) {
        int r = idx >> 6, c = idx & 63;
        float v = L[(size_t)k * DIM * DIM + idx];
        Llds[r * ST + c] = (c <= r) ? v : 0.f;
    }
    for (int idx = t; idx < DIM * ST; idx += 256) {
        Clds[idx] = 0.f;
        Ylds[idx] = 0.f;
    }
    __syncthreads();

    {
        float Lr[DIM];
        const float2* lp = (const float2*)(Llds + ln * ST);
#pragma unroll
        for (int p = 0; p < 32; ++p) {
            float2 v = lp[p];
            Lr[2 * p] = v.x; Lr[2 * p + 1] = v.y;
        }
#pragma unroll 1
        for (int jj = 0; jj < 16; ++jj) {
            const int j = wv * 16 + jj;
            const float2* up = (const float2*)(Llds + j * ST);
            float a0 = 0.f, a1 = 0.f, a2 = 0.f, a3 = 0.f;
#pragma unroll
            for (int p = 0; p < 32; p += 2) {
                float2 u0 = up[p], u1 = up[p + 1];
                a0 = fmaf(Lr[2 * p], u0.x, a0);
                a1 = fmaf(Lr[2 * p + 1], u0.y, a1);
                a2 = fmaf(Lr[2 * p + 2], u1.x, a2);
                a3 = fmaf(Lr[2 * p + 3], u1.y, a3);
            }
            float s = (a0 + a1) + (a2 + a3);
            if (j == ln) s += 1.f;
            Sig[ln * ST + j] = s;
        }
    }
    __syncthreads();

    {
        const float2* crow = (const float2*)(Clds + ln * ST);
        const float2* yrow = (const float2*)(Ylds + ln * ST);
        float ld2 = 0.f;
#pragma unroll 1
        for (int c = 0; c < DIM; c += 4) {
            const float2* u0 = (const float2*)(Clds + (c + 0) * ST);
            const float2* u1 = (const float2*)(Clds + (c + 1) * ST);
            const float2* u2 = (const float2*)(Clds + (c + 2) * ST);
            const float2* u3 = (const float2*)(Clds + (c + 3) * ST);
            float si0 = 0.f, si1 = 0.f, si2 = 0.f, si3 = 0.f;
            if (wv == 0) {
                float d0a = 0.f, d0b = 0.f, d1a = 0.f, d1b = 0.f;
                float d2a = 0.f, d2b = 0.f, d3a = 0.f, d3b = 0.f;
#pragma unroll
                for (int p = 0; p < 32; ++p) {
                    float2 cr = crow[p];
                    float2 a0 = u0[p], a1 = u1[p], a2 = u2[p], a3 = u3[p];
                    d0a = fmaf(cr.x, a0.x, d0a); d0b = fmaf(cr.y, a0.y, d0b);
                    d1a = fmaf(cr.x, a1.x, d1a); d1b = fmaf(cr.y, a1.y, d1b);
                    d2a = fmaf(cr.x, a2.x, d2a); d2b = fmaf(cr.y, a2.y, d2b);
                    d3a = fmaf(cr.x, a3.x, d3a); d3b = fmaf(cr.y, a3.y, d3b);
                }
                const float4 sg = *(const float4*)(Sig + ln * ST + c);
                float s0 = sg.x - (d0a + d0b);
                float s1 = sg.y - (d1a + d1b);
                float s2 = sg.z - (d2a + d2b);
                float s3 = sg.w - (d3a + d3b);
                float dd0 = rdlane(s0, c + 0);
                float rd0 = __builtin_amdgcn_rsqf(dd0);
                float c0v = s0 * rd0;
                s1 = fmaf(-c0v, rdlane(c0v, c + 1), s1);
                s2 = fmaf(-c0v, rdlane(c0v, c + 2), s2);
                s3 = fmaf(-c0v, rdlane(c0v, c + 3), s3);
                float dd1 = rdlane(s1, c + 1);
                float rd1 = __builtin_amdgcn_rsqf(dd1);
                float c1v = s1 * rd1;
                s2 = fmaf(-c1v, rdlane(c1v, c + 2), s2);
                s3 = fmaf(-c1v, rdlane(c1v, c + 3), s3);
                float dd2 = rdlane(s2, c + 2);
                float rd2 = __builtin_amdgcn_rsqf(dd2);
                float c2v = s2 * rd2;
                s3 = fmaf(-c2v, rdlane(c2v, c + 3), s3);
                float dd3 = rdlane(s3, c + 3);
                float rd3 = __builtin_amdgcn_rsqf(dd3);
                float c3v = s3 * rd3;
                ld2 += (__logf(dd0) + __logf(dd1)) + (__logf(dd2) + __logf(dd3));
                *(float4*)(Clds + ln * ST + c) = make_float4(c0v, c1v, c2v, c3v);
                if (ln == 0) *(float4*)(rdbuf + c) = make_float4(rd0, rd1, rd2, rd3);
            } else if (wv == 1) {
                float e0a = 0.f, e0b = 0.f, e1a = 0.f, e1b = 0.f;
                float e2a = 0.f, e2b = 0.f, e3a = 0.f, e3b = 0.f;
#pragma unroll
                for (int p = 0; p < 32; ++p) {
                    float2 yr = yrow[p];
                    float2 a0 = u0[p], a1 = u1[p], a2 = u2[p], a3 = u3[p];
                    e0a = fmaf(yr.x, a0.x, e0a); e0b = fmaf(yr.y, a0.y, e0b);
                    e1a = fmaf(yr.x, a1.x, e1a); e1b = fmaf(yr.y, a1.y, e1b);
                    e2a = fmaf(yr.x, a2.x, e2a); e2b = fmaf(yr.y, a2.y, e2b);
                    e3a = fmaf(yr.x, a3.x, e3a); e3b = fmaf(yr.y, a3.y, e3b);
                }
                si0 = ((ln == c + 0) ? 1.f : 0.f) - (e0a + e0b);
                si1 = ((ln == c + 1) ? 1.f : 0.f) - (e1a + e1b);
                si2 = ((ln == c + 2) ? 1.f : 0.f) - (e2a + e2b);
                si3 = ((ln == c + 3) ? 1.f : 0.f) - (e3a + e3b);
            }
            __syncthreads();
            if (wv == 1) {
                const float4 rdv = *(const float4*)(rdbuf + c);
                float C10 = Clds[(c + 1) * ST + c];
                float C20 = Clds[(c + 2) * ST + c];
                float C21 = Clds[(c + 2) * ST + c + 1];
                float C30 = Clds[(c + 3) * ST + c];
                float C31 = Clds[(c + 3) * ST + c + 1];
                float C32 = Clds[(c + 3) * ST + c + 2];
                float y0 = si0 * rdv.x;
                float y1 = (si1 - C10 * y0) * rdv.y;
                float y2 = (si2 - C20 * y0 - C21 * y1) * rdv.z;
                float y3 = (si3 - C30 * y0 - C31 * y1 - C32 * y2) * rdv.w;
                float4 yo;
                yo.x = (ln <= c + 0) ? y0 : 0.f;
                yo.y = (ln <= c + 1) ? y1 : 0.f;
                yo.z = (ln <= c + 2) ? y2 : 0.f;
                yo.w = (ln <= c + 3) ? y3 : 0.f;
                *(float4*)(Ylds + ln * ST + c) = yo;
            }
        }
        if (wv == 0 && ln == 0) ldet = ld2;
    }
    __syncthreads();

    if (wv == 0) {
        const float* muk = mu + k * DIM;
        float qv = 0.f;
#pragma unroll 8
        for (int j = 0; j < DIM; ++j)
            qv = fmaf(Ylds[j * ST + ln], muk[j], qv);
        qlds[ln] = qv;
        if (ln == 0) {
            float wm = -3.0e38f;
            for (int i = 0; i < KC; ++i) wm = fmaxf(wm, w[i]);
            float se = 0.f;
            for (int i = 0; i < KC; ++i) se += __expf(w[i] - wm);
            float logw = w[k] - (wm + __logf(se));
            cstC[k] = -0.5f * (DIM * LOG_2PI + ldet) + logw - C0;
        }
    }
    __syncthreads();

    {
        const int ct = wv;
        const int col = ct * 16 + (ln & 15);
        const int kb = (ln >> 4) * 8;
#pragma unroll
        for (int kt = 0; kt < 3; ++kt) {
            short8 v;
            if (kt < 2) {
#pragma unroll
                for (int e = 0; e < 8; ++e)
                    v[e] = (short)f2bf(Ylds[(kt * 32 + kb + e) * ST + col]);
            } else {
#pragma unroll
                for (int e = 0; e < 8; ++e)
                    v[e] = (short)((kb + e == 0) ? f2bf(-qlds[col]) : 0);
            }
            *(short8*)(Bpack + ((size_t)(k * 12 + ct * 3 + kt) * 64 + ln) * 8) = v;
        }
    }
}

// ============================================================================
// Main: r8 verbatim (measured best: LDS-staged B, (256,2), scalar X loads,
// DPP sum16) with ONE change: the augmented-tile MFMAs are dropped by
// initializing the accumulator to {nq,nq,nq,nq} (MFMA computes A*B + C_init,
// so the -q fold is free). nq = bf16(-q[ct*16+m]) read from the staged aug
// fragment in LDS (indexing HW-verified by r11's pass). Per wave: -32 MFMA,
// -16 ds_read_b128, +16 ds_read_u16 (2-way bank alias = free).
// ============================================================================
__global__ __launch_bounds__(256, 2) void main_kernel(
    const float* __restrict__ X, const float* __restrict__ Bpack,
    const float* __restrict__ cstC, float* __restrict__ partials)
{
    const int tid = threadIdx.x;
    const int lane = tid & 63;
    const int wv = tid >> 6;
    const int ks = blockIdx.x & 7;         // k in [4ks, 4ks+4)
    const int g = blockIdx.x >> 3;         // row group: 128 rows
    const int m = lane & 15;

    __shared__ float4 Bsh[3072];           // 48 KB
    {
        const float4* Bg = (const float4*)Bpack + (size_t)ks * 3072;
#pragma unroll
        for (int it = 0; it < 12; ++it)
            Bsh[it * 256 + tid] = Bg[it * 256 + tid];
    }

    const int rbase = g * 128 + wv * 32;
    const int jb = (lane >> 4) * 8;
    const float* Xr0 = X + (size_t)(rbase + m) * DIM;
    const float* Xr1 = Xr0 + 16 * DIM;
    short8 a0, a1, b0r, b1r;
#pragma unroll
    for (int e = 0; e < 8; ++e) {
        a0[e] = (short)f2bf(Xr0[jb + e]);
        a1[e] = (short)f2bf(Xr0[32 + jb + e]);
        b0r[e] = (short)f2bf(Xr1[jb + e]);
        b1r[e] = (short)f2bf(Xr1[32 + jb + e]);
    }

    __syncthreads();

    const short8* Bs = (const short8*)Bsh;
    const short* Bss = (const short*)Bsh;
    float acc = 0.f;
#pragma unroll
    for (int kk = 0; kk < 4; ++kk) {
        const int k = ks * 4 + kk;
        float p0 = 0.f, p1 = 0.f, p2 = 0.f, p3 = 0.f;
        float r0 = 0.f, r1 = 0.f, r2 = 0.f, r3 = 0.f;
#pragma unroll
        for (int ct = 0; ct < 4; ++ct) {
            short8 f0 = Bs[(kk * 12 + ct * 3 + 0) * 64 + lane];
            short8 f1 = Bs[(kk * 12 + ct * 3 + 1) * 64 + lane];
            // bf16(-q[k][ct*16+m]) from the staged aug fragment (lane m, elem 0)
            short nqs = Bss[(size_t)((kk * 12 + ct * 3 + 2) * 64 + m) * 8];
            float nq = __int_as_float(((int)(unsigned short)nqs) << 16);
            float4v c0 = {nq, nq, nq, nq};   // -q folded via accumulator init
            c0 = __builtin_amdgcn_mfma_f32_16x16x32_bf16(a0, f0, c0, 0, 0, 0);
            c0 = __builtin_amdgcn_mfma_f32_16x16x32_bf16(a1, f1, c0, 0, 0, 0);
            float4v c1 = {nq, nq, nq, nq};
            c1 = __builtin_amdgcn_mfma_f32_16x16x32_bf16(b0r, f0, c1, 0, 0, 0);
            c1 = __builtin_amdgcn_mfma_f32_16x16x32_bf16(b1r, f1, c1, 0, 0, 0);
            p0 = fmaf(c0[0], c0[0], p0); p1 = fmaf(c0[1], c0[1], p1);
            p2 = fmaf(c0[2], c0[2], p2); p3 = fmaf(c0[3], c0[3], p3);
            r0 = fmaf(c1[0], c1[0], r0); r1 = fmaf(c1[1], c1[1], r1);
            r2 = fmaf(c1[2], c1[2], r2); r3 = fmaf(c1[3], c1[3], r3);
        }
        const float cc = cstC[k];          // wave-uniform s_load
        acc += __expf(fmaf(-0.5f, sum16(p0), cc)) + __expf(fmaf(-0.5f, sum16(p1), cc));
        acc += __expf(fmaf(-0.5f, sum16(p2), cc)) + __expf(fmaf(-0.5f, sum16(p3), cc));
        acc += __expf(fmaf(-0.5f, sum16(r0), cc)) + __expf(fmaf(-0.5f, sum16(r1), cc));
        acc += __expf(fmaf(-0.5f, sum16(r2), cc)) + __expf(fmaf(-0.5f, sum16(r3), cc));
    }
    // the 4 lane-groups hold disjoint rows (in-group duplicates after sum16)
    acc += __shfl_xor(acc, 16, 64);
    acc += __shfl_xor(acc, 32, 64);

    __shared__ float pm[4];
    if (lane == 0) pm[wv] = acc;
    __syncthreads();
    if (tid == 0)
        partials[blockIdx.x] = (pm[0] + pm[1]) + (pm[2] + pm[3]);
}

// ============================================================================
// Final: sum 2048 partials -> out = -(C0 + log(S))
// ============================================================================
__global__ __launch_bounds__(256) void final_kernel(
    const float* __restrict__ partials, int n, float* __restrict__ out)
{
    const int tid = threadIdx.x;
    float s = 0.f;
    for (int i = tid; i < n; i += 256) s += partials[i];
#pragma unroll
    for (int mm = 1; mm <= 32; mm <<= 1) s += __shfl_xor(s, mm, 64);
    __shared__ float pm[4];
    if ((tid & 63) == 0) pm[tid >> 6] = s;
    __syncthreads();
    if (tid == 0) out[0] = -(C0 + logf((pm[0] + pm[1]) + (pm[2] + pm[3])));
}

extern "C" void kernel_launch(void* const* d_in, const int* in_sizes, int n_in,
                              void* d_out, int out_size, void* d_ws, size_t ws_size,
                              hipStream_t stream) {
    const float* X  = (const float*)d_in[0];   // [32768,64]
    const float* mu = (const float*)d_in[1];   // [32,64]
    const float* L  = (const float*)d_in[2];   // [32,64,64]
    const float* w  = (const float*)d_in[3];   // [32]
    // d_in[4] = it (unused)

    char* ws = (char*)d_ws;
    short* Bpack = (short*)ws;                         // 32*12*64*8 bf16 = 384 KB
    float* cstC  = (float*)(ws + 32 * 12 * 64 * 8 * 2);
    float* parts = cstC + KC;                          // 2048 floats

    prep_kernel<<<KC, 256, 0, stream>>>(L, mu, w, Bpack, cstC);
    main_kernel<<<2048, 256, 0, stream>>>(X, (const float*)Bpack, cstC, parts);
    final_kernel<<<1, 256, 0, stream>>>(parts, 2048, (float*)d_out);
}